// Round 1
// baseline (449.090 us; speedup 1.0000x reference)
//
#include <hip/hip_runtime.h>

// GraphAttentionLayer v3: B=16, M=2048, F_IN=128, F_OUT=64, ALPHA=0.2
// out = elu( softmax_j( mask(adj, leaky_relu(f1_i + f2_j)) ) @ (h@W) )
// Algebra: h' = ((P @ h) @ W)/den, f1 = h@(W@a1), f2 = h@(W@a2).
//
// v3 restructure vs v2 (178 us/dispatch, 30% of cycles in LDS bank conflicts,
// 40% VALUBusy on redundant staging):
//  - ROWS 32->64, 512 threads (8 waves), 512 blocks: halves per-batch staging
//    redundancy (each block converts h[b] once -> 2x fewer f2bf overall).
//  - P (A-fragment) computed IN REGISTERS per wave (wave w: row group w&3,
//    feat half w>>2). No P LDS tile, no P write conflicts, one less barrier.
//  - f2 precomputed once per block into f2all[2048] (same summation order as
//    v2's per-tile f2 -> bit-identical scores).
//  - hT staging writes XOR-swizzled: dword slot = tq ^ ((k>>3)&12). Write
//    banks 2-way (free); read de-swizzles via quad^swz (swizzle closed in
//    {0,4,8,12} so b64 reads stay contiguous & aligned).
//  - ONE raw barrier per iter (lgkmcnt(0) + s_barrier, no vmcnt drain) with
//    double-buffered hT; adj prefetched 2 tiles ahead, h 1 tile ahead, kept
//    in flight across barriers.
// LDS 52 KB static; epilogue identical numerics to v2 (bf16 Wl).

#define M_     2048
#define FIN_   128
#define F_     64
#define ALPHA_ 0.2f
#define ROWS_  64
#define TS_    36      // hT token stride in u16 (72 B rows: 18 dwords, odd-ish spread)
#define WT_    132     // Tsum row stride in floats

typedef float  float4_ __attribute__((ext_vector_type(4)));
typedef short  short4_ __attribute__((ext_vector_type(4)));
typedef short  short8  __attribute__((ext_vector_type(8)));
typedef int    int4_   __attribute__((ext_vector_type(4)));
typedef unsigned short u16;
typedef unsigned int   u32;

static __device__ __forceinline__ float bf2f(u16 u) {
    return __uint_as_float(((u32)u) << 16);
}
static __device__ __forceinline__ u16 f2bf(float f) {
    u32 u = __float_as_uint(f);
    u32 r = u + 0x7FFFu + ((u >> 16) & 1u);
    return (u16)(r >> 16);
}

__global__ __launch_bounds__(512, 4) void k_gat3(
    const float* __restrict__ h, const int* __restrict__ adj,
    const float* __restrict__ W, const float* __restrict__ a,
    float* __restrict__ out)
{
    __shared__ u16   Wl[FIN_ * F_];          // 16 KB  W bf16 (epilogue)
    __shared__ float a_s[2 * F_];            // 512 B
    __shared__ float wa1[FIN_], wa2[FIN_];   // 1 KB
    __shared__ float f1s[ROWS_];             // 256 B
    __shared__ float dens[ROWS_];            // 256 B
    __shared__ char  dyn[WT_ * 64 * 4];      // 33792 B (loop bufs / Tsum alias)

    u16*   hTbuf0 = (u16*)dyn;               // [128][TS_] 9216 B
    u16*   hTbuf1 = (u16*)(dyn + 9216);      // [128][TS_] 9216 B
    float* f2all  = (float*)(dyn + 18432);   // [2048]     8192 B
    float* Tsum   = (float*)dyn;             // [64][WT_]  (epilogue only)

    const int tid  = threadIdx.x;
    const int w    = tid >> 6;
    const int l    = tid & 63;
    const int lc   = l & 15;
    const int quad = l >> 4;
    const int b    = blockIdx.x >> 5;
    const int i0   = (blockIdx.x & 31) * ROWS_;

    // ---------------- stage a, W (bf16) --------------------------------------
    if (tid < 128) a_s[tid] = a[tid];
    for (int e = tid; e < FIN_ * F_; e += 512) Wl[e] = f2bf(W[e]);
    __syncthreads();

    // ---------------- wa1/wa2 = W @ a1, W @ a2 (fp32) ------------------------
    if (tid < FIN_) {
        float s1 = 0.f, s2 = 0.f;
#pragma unroll 8
        for (int n = 0; n < F_; ++n) {
            float wv = W[tid * F_ + n];
            s1 += wv * a_s[n];
            s2 += wv * a_s[F_ + n];
        }
        wa1[tid] = s1;
        wa2[tid] = s2;
    }
    __syncthreads();

    // ---------------- f1 for this block's 64 rows ----------------------------
    {
        const int r = tid >> 3, k0 = (tid & 7) * 16;
        const float* hp = h + ((size_t)(b * M_ + i0 + r)) * FIN_ + k0;
        float s = 0.f;
#pragma unroll
        for (int k = 0; k < 16; ++k) s += hp[k] * wa1[k0 + k];
        s += __shfl_xor(s, 1, 64);
        s += __shfl_xor(s, 2, 64);
        s += __shfl_xor(s, 4, 64);
        if ((tid & 7) == 0) f1s[r] = s;
    }

    // ---------------- f2 for ALL 2048 tokens (once per block) ----------------
    // Same per-lane serial-8 + 16-lane xor tree as v2 -> bit-identical f2.
    {
        const int sf0 = (tid & 15) * 8;
        for (int p = 0; p < 64; ++p) {
            const int t = p * 32 + (tid >> 4);
            const float* hp = h + ((size_t)(b * M_ + t)) * FIN_ + sf0;
            float4_ x0 = *(const float4_*)hp;
            float4_ x1 = *(const float4_*)(hp + 4);
            float fp = 0.f;
            fp += x0[0] * wa2[sf0 + 0]; fp += x0[1] * wa2[sf0 + 1];
            fp += x0[2] * wa2[sf0 + 2]; fp += x0[3] * wa2[sf0 + 3];
            fp += x1[0] * wa2[sf0 + 4]; fp += x1[1] * wa2[sf0 + 5];
            fp += x1[2] * wa2[sf0 + 6]; fp += x1[3] * wa2[sf0 + 7];
            fp += __shfl_xor(fp, 1, 64);
            fp += __shfl_xor(fp, 2, 64);
            fp += __shfl_xor(fp, 4, 64);
            fp += __shfl_xor(fp, 8, 64);
            if ((tid & 15) == 0) f2all[t] = fp;
        }
    }

    // ---------------- per-thread roles ---------------------------------------
    const int rg  = w & 3;            // wave's 16-row group (0..3)
    const int nh  = w >> 2;           // wave's feature half (0..1)
    const int tq  = tid >> 5;         // staging: token pair (2tq, 2tq+1), 0..15
    const int f0  = (tid & 31) * 4;   // staging: feature quartet
    const int row = i0 + rg * 16 + lc;

    const int*   aprow  = adj + ((size_t)(b * M_ + row)) * M_ + quad * 8;
    const float* hstage = h + ((size_t)(b * M_ + 2 * tq)) * FIN_ + f0;

    // prologue prefetch: adj tiles 0,1 and h tile 0 (drained once at the sync)
    int4_   aA0 = *(const int4_*)(aprow);
    int4_   aA1 = *(const int4_*)(aprow + 4);
    int4_   aB0 = *(const int4_*)(aprow + 32);
    int4_   aB1 = *(const int4_*)(aprow + 36);
    float4_ hA0 = *(const float4_*)(hstage);
    float4_ hA1 = *(const float4_*)(hstage + FIN_);

    __syncthreads();   // f1s / f2all ready

    const float f1r = f1s[rg * 16 + lc];
    float denacc = 0.f;
    float4_ acc0 = {0.f,0.f,0.f,0.f}, acc1 = {0.f,0.f,0.f,0.f};
    float4_ acc2 = {0.f,0.f,0.f,0.f}, acc3 = {0.f,0.f,0.f,0.f};

    for (int t = 0; t < 64; ++t) {
        u16* hT = (t & 1) ? hTbuf1 : hTbuf0;
        const int j0 = t * 32;
        const int jn = (t < 63 ? t + 1 : 63) * 32;   // h prefetch (depth 1)
        const int jp = (t < 62 ? t + 2 : 63) * 32;   // adj prefetch (depth 2)

        // ---- issue prefetches; they stay in flight across the raw barrier ----
        int4_   aC0 = *(const int4_*)(aprow + jp);
        int4_   aC1 = *(const int4_*)(aprow + jp + 4);
        float4_ hN0 = *(const float4_*)(hstage + (size_t)jn * FIN_);
        float4_ hN1 = *(const float4_*)(hstage + (size_t)jn * FIN_ + FIN_);

        // ---- stage h(t) tile: bf16 [feat][token], XOR-swizzled dword slots ----
        // write banks: 16*(q&1) + 20*kk-ish + (tq ^ (q-bits)) -> 2-way (free)
#pragma unroll
        for (int kk = 0; kk < 4; ++kk) {
            const int k   = f0 + kk;
            const int swz = (k >> 3) & 12;
            u32 pk = (u32)f2bf(hA0[kk]) | ((u32)f2bf(hA1[kk]) << 16);
            *(u32*)(hT + k * TS_ + 2 * (tq ^ swz)) = pk;
        }

        // producer drain + raw barrier (NO vmcnt drain -> prefetches live on)
        asm volatile("s_waitcnt lgkmcnt(0)" ::: "memory");
        __builtin_amdgcn_s_barrier();
        __builtin_amdgcn_sched_barrier(0);

        // ---- scores for (row, tokens j0+quad*8..+7): A-frag in registers ----
        float4_ g0 = *(const float4_*)(f2all + j0 + quad * 8);
        float4_ g1 = *(const float4_*)(f2all + j0 + quad * 8 + 4);
        short8 af;
        float d = 0.f;
#define SCORE(J, GV, AV)                                   \
        {                                                  \
            float x_ = f1r + (GV);                         \
            x_ = fmaxf(x_, ALPHA_ * x_);                   \
            float e_ = ((AV) > 0) ? __expf(x_) : 0.f;      \
            u16 pb = f2bf(e_);                             \
            d += bf2f(pb);                                 \
            af[J] = (short)pb;                             \
        }
        SCORE(0, g0[0], aA0[0]) SCORE(1, g0[1], aA0[1])
        SCORE(2, g0[2], aA0[2]) SCORE(3, g0[3], aA0[3])
        SCORE(4, g1[0], aA1[0]) SCORE(5, g1[1], aA1[1])
        SCORE(6, g1[2], aA1[2]) SCORE(7, g1[3], aA1[3])
#undef SCORE
        denacc += d;

        // ---- MFMA: 4 feature tiles of this wave's half; B de-swizzled ----
#define MTILE(C, ACC)                                                        \
        {                                                                    \
            const int fidx = (nh * 4 + (C)) * 16 + lc;                       \
            const int swzf = ((nh * 4 + (C)) * 2) & 12;                      \
            const u16* bp = hT + fidx * TS_ + (((quad * 4) ^ swzf) << 1);    \
            short4_ b0 = *(const short4_*)bp;                                \
            short4_ b1 = *(const short4_*)(bp + 4);                          \
            short8 bf;                                                       \
            bf[0] = b0[0]; bf[1] = b0[1]; bf[2] = b0[2]; bf[3] = b0[3];      \
            bf[4] = b1[0]; bf[5] = b1[1]; bf[6] = b1[2]; bf[7] = b1[3];      \
            ACC = __builtin_amdgcn_mfma_f32_16x16x32_bf16(af, bf, ACC, 0, 0, 0); \
        }
        MTILE(0, acc0) MTILE(1, acc1) MTILE(2, acc2) MTILE(3, acc3)
#undef MTILE

        // rotate prefetch registers
        aA0 = aB0; aA1 = aB1; aB0 = aC0; aB1 = aC1;
        hA0 = hN0; hA1 = hN1;
    }

    // ---------------- denom: reduce over the 4 quads -------------------------
    denacc += __shfl_xor(denacc, 16, 64);
    denacc += __shfl_xor(denacc, 32, 64);
    if (nh == 0 && quad == 0) dens[rg * 16 + lc] = denacc;
    __syncthreads();   // full drain; loop buffers dead, Tsum alias safe

    // ---------------- T -> LDS (disjoint per wave) ---------------------------
#pragma unroll
    for (int mm = 0; mm < 4; ++mm) {
        const int rr = (rg * 16 + quad * 4 + mm) * WT_ + nh * 64 + lc;
        Tsum[rr +  0] = acc0[mm];
        Tsum[rr + 16] = acc1[mm];
        Tsum[rr + 32] = acc2[mm];
        Tsum[rr + 48] = acc3[mm];
    }
    __syncthreads();

    // ---------------- epilogue: out = elu( (T @ W) / den ) -------------------
    {
        const int r  = tid >> 3;
        const int n0 = (tid & 7) * 8;
        const float den  = dens[r];
        const float rden = (den > 0.f) ? (1.f / den) : 0.f;
        float u[8];
#pragma unroll
        for (int nn = 0; nn < 8; ++nn) u[nn] = 0.f;
        for (int k = 0; k < FIN_; ++k) {
            const float tv = Tsum[r * WT_ + k];
            short8 wv = *(const short8*)(Wl + k * F_ + n0);
#pragma unroll
            for (int nn = 0; nn < 8; ++nn) u[nn] += tv * bf2f((u16)wv[nn]);
        }
        float4_ o0, o1;
#pragma unroll
        for (int nn = 0; nn < 8; ++nn) {
            float hp = u[nn] * rden;
            float o  = hp > 0.f ? hp : expm1f(hp);
            if (nn < 4) o0[nn] = o; else o1[nn - 4] = o;
        }
        float* op = out + ((size_t)(b * M_ + i0 + r)) * F_ + n0;
        *(float4_*)op       = o0;
        *(float4_*)(op + 4) = o1;
    }
}

// ---------------------------------------------------------------------------
extern "C" void kernel_launch(void* const* d_in, const int* in_sizes, int n_in,
                              void* d_out, int out_size, void* d_ws, size_t ws_size,
                              hipStream_t stream)
{
    (void)out_size; (void)d_ws; (void)ws_size;
    const float* h  = (const float*)d_in[0];
    const int* adjp = (const int*)d_in[1];
    const float* Wp = (const float*)d_in[2];
    const float* ap = (const float*)d_in[3];
    for (int i = 0; i < n_in; ++i) {
        long s = in_sizes[i];
        if      (s == 4194304L)  h    = (const float*)d_in[i];
        else if (s == 67108864L) adjp = (const int*)d_in[i];
        else if (s == 8192L)     Wp   = (const float*)d_in[i];
        else if (s == 128L)      ap   = (const float*)d_in[i];
    }
    k_gat3<<<512, 512, 0, stream>>>(h, adjp, Wp, ap, (float*)d_out);
}